// Round 6
// baseline (991.122 us; speedup 1.0000x reference)
//
#include <hip/hip_runtime.h>
#include <hip/hip_bf16.h>
#include <math.h>

// Problem dims
#define CC 128          // C
#define DI 256          // D_INNER
#define SSEQ 256        // B*N sequences
#define ROWS 65536      // SSEQ*TT

typedef __hip_bfloat16 bf16;
typedef __attribute__((ext_vector_type(8))) short short8;   // 8 bf16 (4 VGPRs) MFMA A/B frag
typedef __attribute__((ext_vector_type(4))) float float4v;  // MFMA C/D frag

__device__ __forceinline__ float to_f(float v) { return v; }
__device__ __forceinline__ float to_f(bf16 v)  { return __bfloat162float(v); }
__device__ __forceinline__ bf16  f2b(float v)  { return __float2bfloat16(v); }

__device__ __forceinline__ float wave_sum(float v) {
    #pragma unroll
    for (int o = 1; o < 64; o <<= 1) v += __shfl_xor(v, o, 64);
    return v;
}
__device__ __forceinline__ float silu_f(float x) { return x / (1.f + __expf(-x)); }
__device__ __forceinline__ float gelu_f(float x) { return 0.5f * x * (1.f + erff(x * 0.70710678118654752f)); }
__device__ __forceinline__ float softplus_f(float x) {
    return (x > 20.f) ? x : __logf(1.f + __expf(x));
}

// ---------------- LN1: x (B,T,N,C) fp32 -> bf16 rows in (s,t) order, s = b*64+n ----------------
__global__ __launch_bounds__(256) void ln1_kernel(const float* __restrict__ x,
                                                  const float* __restrict__ g,
                                                  const float* __restrict__ b,
                                                  bf16* __restrict__ out) {
    int wave = threadIdx.x >> 6, lane = threadIdx.x & 63;
    int r = blockIdx.x * 4 + wave;
    int s = r >> 8, t = r & 255;
    int bb = s >> 6, n = s & 63;
    size_t xbase = (((size_t)(bb * 256 + t)) * 64 + n) * CC;
    float v0 = x[xbase + lane], v1 = x[xbase + lane + 64];
    float s1 = wave_sum(v0 + v1);
    float s2 = wave_sum(v0 * v0 + v1 * v1);
    float m = s1 * (1.f / 128.f);
    float var = s2 * (1.f / 128.f) - m * m;
    float rstd = rsqrtf(var + 1e-5f);
    size_t ob = (size_t)r * CC;
    out[ob + lane]      = f2b((v0 - m) * rstd * g[lane]      + b[lane]);
    out[ob + lane + 64] = f2b((v1 - m) * rstd * g[lane + 64] + b[lane + 64]);
}

// ---------------- LN3: fp32 row-major in -> bf16 out ----------------
__global__ __launch_bounds__(256) void ln3_kernel(const float* __restrict__ in,
                                                  const float* __restrict__ g,
                                                  const float* __restrict__ b,
                                                  bf16* __restrict__ out) {
    int wave = threadIdx.x >> 6, lane = threadIdx.x & 63;
    int r = blockIdx.x * 4 + wave;
    size_t ib = (size_t)r * CC;
    float v0 = in[ib + lane], v1 = in[ib + lane + 64];
    float s1 = wave_sum(v0 + v1);
    float s2 = wave_sum(v0 * v0 + v1 * v1);
    float m = s1 * (1.f / 128.f);
    float var = s2 * (1.f / 128.f) - m * m;
    float rstd = rsqrtf(var + 1e-5f);
    out[ib + lane]      = f2b((v0 - m) * rstd * g[lane]      + b[lane]);
    out[ib + lane + 64] = f2b((v1 - m) * rstd * g[lane + 64] + b[lane + 64]);
}

// ================= MFMA GEMM, 64x64 tile, 256 threads (4 waves) =================
template <bool BTR, int EPI, int KTILES>
__global__ __launch_bounds__(256) void mfma_gemm_kernel(const bf16* __restrict__ A, int lda,
                                                        const float* __restrict__ B,
                                                        const float* __restrict__ bias,
                                                        void* __restrict__ Cout, int ldc,
                                                        int N, int K) {
    __shared__ bf16 As[64][40];
    __shared__ bf16 Bs[64][40];
    int tid = threadIdx.x;
    int m0 = blockIdx.x * 64;
    int n0 = blockIdx.y * 64;
    int wv = tid >> 6, lane = tid & 63;
    int lrow = lane & 15, quad = lane >> 4;
    int lk = quad * 8;
    float4v acc[4] = {};
    #pragma unroll
    for (int kt = 0; kt < KTILES; kt++) {
        int k0 = kt * 32;
        {
            int m = tid >> 2, part = tid & 3;
            uint4 v = *(const uint4*)(A + (size_t)(m0 + m) * lda + k0 + part * 8);
            *(uint4*)&As[m][part * 8] = v;
        }
        if (BTR) {
            int n = tid >> 2, part = tid & 3;
            const float* src = B + (size_t)(n0 + n) * K + k0 + part * 8;
            bf16 tmp[8];
            #pragma unroll
            for (int j = 0; j < 8; j++) tmp[j] = f2b(src[j]);
            *(uint4*)&Bs[n][part * 8] = *(uint4*)tmp;
        } else {
            int kk = tid >> 3, nf = (tid & 7) * 8;
            const float* src = B + (size_t)(k0 + kk) * N + n0 + nf;
            #pragma unroll
            for (int j = 0; j < 8; j++) Bs[nf + j][kk] = f2b(src[j]);
        }
        __syncthreads();
        short8 a = *(const short8*)&As[wv * 16 + lrow][lk];
        #pragma unroll
        for (int jt = 0; jt < 4; jt++) {
            short8 bfr = *(const short8*)&Bs[jt * 16 + lrow][lk];
            acc[jt] = __builtin_amdgcn_mfma_f32_16x16x32_bf16(a, bfr, acc[jt], 0, 0, 0);
        }
        __syncthreads();
    }
    #pragma unroll
    for (int jt = 0; jt < 4; jt++) {
        int col = n0 + jt * 16 + lrow;
        float bs = (EPI >= 1) ? bias[col] : 0.f;
        #pragma unroll
        for (int r = 0; r < 4; r++) {
            int row = m0 + wv * 16 + quad * 4 + r;
            float v = acc[jt][r] + bs;
            if (EPI == 1) v = gelu_f(v);
            if (EPI == 2) {
                float* Cf = (float*)Cout;
                Cf[(size_t)row * ldc + col] += v;
            } else {
                bf16* Cb = (bf16*)Cout;
                Cb[(size_t)row * ldc + col] = f2b(v);
            }
        }
    }
}

// ======== MFMA W_out GEMM (64x128 tile) with fused LN2 + residual epilogue ========
__global__ __launch_bounds__(256) void mfma_ln2res_kernel(const bf16* __restrict__ xz,
                                                          const float* __restrict__ Wout,
                                                          const float* __restrict__ g,
                                                          const float* __restrict__ b,
                                                          const float* __restrict__ x,
                                                          float* __restrict__ out) {
    __shared__ bf16 As[64][40];
    __shared__ bf16 Bs[128][40];
    int tid = threadIdx.x;
    int m0 = blockIdx.x * 64;
    int wv = tid >> 6, lane = tid & 63;
    int lrow = lane & 15, quad = lane >> 4;
    int lk = quad * 8;
    float4v acc[8] = {};
    #pragma unroll
    for (int kt = 0; kt < 8; kt++) {          // K = 256
        int k0 = kt * 32;
        {
            int m = tid >> 2, part = tid & 3;
            uint4 v = *(const uint4*)(xz + (size_t)(m0 + m) * 512 + 256 + k0 + part * 8);
            *(uint4*)&As[m][part * 8] = v;
        }
        #pragma unroll
        for (int it = 0; it < 2; it++) {
            int idx = tid + it * 256;
            int n = idx >> 2, part = idx & 3;
            const float* src = Wout + (size_t)n * 256 + k0 + part * 8;
            bf16 tmp[8];
            #pragma unroll
            for (int j = 0; j < 8; j++) tmp[j] = f2b(src[j]);
            *(uint4*)&Bs[n][part * 8] = *(uint4*)tmp;
        }
        __syncthreads();
        short8 a = *(const short8*)&As[wv * 16 + lrow][lk];
        #pragma unroll
        for (int jt = 0; jt < 8; jt++) {
            short8 bfr = *(const short8*)&Bs[jt * 16 + lrow][lk];
            acc[jt] = __builtin_amdgcn_mfma_f32_16x16x32_bf16(a, bfr, acc[jt], 0, 0, 0);
        }
        __syncthreads();
    }
    #pragma unroll
    for (int r = 0; r < 4; r++) {
        float ps = 0.f, ps2 = 0.f;
        #pragma unroll
        for (int jt = 0; jt < 8; jt++) { float v = acc[jt][r]; ps += v; ps2 += v * v; }
        #pragma unroll
        for (int o = 1; o < 16; o <<= 1) {
            ps  += __shfl_xor(ps, o, 64);
            ps2 += __shfl_xor(ps2, o, 64);
        }
        float m = ps * (1.f / 128.f);
        float var = ps2 * (1.f / 128.f) - m * m;
        float rstd = rsqrtf(var + 1e-5f);
        int row = m0 + wv * 16 + quad * 4 + r;
        int s = row >> 8, t = row & 255;
        int bb = s >> 6, n = s & 63;
        size_t xbase = (((size_t)(bb * 256 + t)) * 64 + n) * CC;
        #pragma unroll
        for (int jt = 0; jt < 8; jt++) {
            int col = jt * 16 + lrow;
            out[xbase + col] = (acc[jt][r] - m) * rstd * g[col] + b[col] + x[xbase + col];
        }
    }
}

// ---------------- xdbl GEMM with fused causal conv + SiLU A-staging (VALU, N=40, fp32 out) ----------------
template <int DIR>
__global__ __launch_bounds__(256) void gemm_conv_kernel(const bf16* __restrict__ xz,
                                                        const float* __restrict__ cw,
                                                        const float* __restrict__ cb,
                                                        const float* __restrict__ B,
                                                        float* __restrict__ C) {
    __shared__ float As[16][65];
    __shared__ float Bs[16][65];
    int tid = threadIdx.x;
    int m0 = blockIdx.x * 64;
    int tx = tid & 15, ty = tid >> 4;
    float acc[4][4] = {};
    for (int k0 = 0; k0 < 256; k0 += 16) {
        #pragma unroll
        for (int r = 0; r < 4; r++) {
            int idx = tid + r * 256;
            int m = idx >> 4, kk = idx & 15;
            int row = m0 + m;
            int t = row & 255, s = row >> 8;
            int d = k0 + kk;
            float a = cb[d];
            #pragma unroll
            for (int j = 0; j < 4; j++) {
                int tj = t - 3 + j;
                if (tj >= 0) {
                    int src = DIR ? (255 - tj) : tj;
                    a += cw[d * 4 + j] * to_f(xz[(size_t)(s * 256 + src) * 512 + d]);
                }
            }
            As[kk][m] = silu_f(a);
        }
        #pragma unroll
        for (int r = 0; r < 4; r++) {
            int idx = tid + r * 256;
            int n = idx >> 4, kk = idx & 15;
            Bs[kk][n] = (n < 40) ? B[(size_t)n * 256 + k0 + kk] : 0.f;
        }
        __syncthreads();
        #pragma unroll
        for (int k = 0; k < 16; k++) {
            float a[4], bv[4];
            #pragma unroll
            for (int i = 0; i < 4; i++) a[i] = As[k][ty * 4 + i];
            #pragma unroll
            for (int j = 0; j < 4; j++) bv[j] = Bs[k][tx * 4 + j];
            #pragma unroll
            for (int i = 0; i < 4; i++)
                #pragma unroll
                for (int j = 0; j < 4; j++) acc[i][j] += a[i] * bv[j];
        }
        __syncthreads();
    }
    #pragma unroll
    for (int i = 0; i < 4; i++) {
        int row = m0 + ty * 4 + i;
        #pragma unroll
        for (int j = 0; j < 4; j++) {
            int col = tx * 4 + j;
            if (col < 40) C[(size_t)row * 40 + col] = acc[i][j];
        }
    }
}

// ---------------- Dual selective scan v2 ----------------
// One block per (sequence, d-quarter); 64 threads, d = q*64+tid.
// xdbl rows are fp32 at wave-uniform addresses -> scalar loads, no LDS/barriers per step.
// Distance-2 register prefetch on all per-step global loads.
// Phase A: backward scan, ungated y_b -> LDS at original time.
// Phase B: forward scan, gated (y_f+y_b)*silu(z) written IN PLACE into z-columns of xz.
__global__ __launch_bounds__(64) void scan_dual_kernel(bf16* __restrict__ xz,
        const float* __restrict__ xdbl_f, const float* __restrict__ xdbl_b,
        const float* __restrict__ cw_f, const float* __restrict__ cb_f,
        const float* __restrict__ Wdt_f, const float* __restrict__ bdt_f,
        const float* __restrict__ Alog_f, const float* __restrict__ D_f,
        const float* __restrict__ cw_b, const float* __restrict__ cb_b,
        const float* __restrict__ Wdt_b, const float* __restrict__ bdt_b,
        const float* __restrict__ Alog_b, const float* __restrict__ D_b) {
    __shared__ bf16 ybuf[256 * 64];   // y_b (ungated) indexed by ORIGINAL time
    int tid = threadIdx.x;
    int s = blockIdx.x >> 2, q = blockIdx.x & 3;
    int d = q * 64 + tid;
    const bf16* xcol = xz + d;              // xc column for this thread
    const bf16* zcol = xz + 256 + d;        // z column

    // ---- Phase A: backward ----
    {
        float A[16], wdt[8];
        #pragma unroll
        for (int n = 0; n < 16; n++) A[n] = -__expf(Alog_b[d * 16 + n]);
        #pragma unroll
        for (int r = 0; r < 8; r++) wdt[r] = Wdt_b[d * 8 + r];
        float bd = bdt_b[d], Dd = D_b[d];
        float c0 = cw_b[d * 4], c1 = cw_b[d * 4 + 1], c2 = cw_b[d * 4 + 2], c3 = cw_b[d * 4 + 3];
        float cb = cb_b[d];
        const float* xrow = xdbl_b + (size_t)s * 256 * 40;   // uniform base
        float h[16];
        #pragma unroll
        for (int n = 0; n < 16; n++) h[n] = 0.f;
        float w0 = 0.f, w1 = 0.f, w2 = 0.f, w3 = 0.f;
        // distance-2 prefetch of xc (orig = 255-t)
        float xc0 = to_f(xcol[(size_t)(s * 256 + 255) * 512]);
        float xc1 = to_f(xcol[(size_t)(s * 256 + 254) * 512]);
        for (int t = 0; t < 256; t++) {
            int orig = 255 - t;
            float xc = xc0;
            xc0 = xc1;
            if (t + 2 < 256) xc1 = to_f(xcol[(size_t)(s * 256 + orig - 2) * 512]);
            const float* row = xrow + t * 40;                // uniform -> s_load
            w0 = w1; w1 = w2; w2 = w3; w3 = xc;
            float u = silu_f(cb + c0 * w0 + c1 * w1 + c2 * w2 + c3 * w3);
            float dtr = bd;
            #pragma unroll
            for (int r = 0; r < 8; r++) dtr += row[r] * wdt[r];
            float dt = softplus_f(dtr);
            float du = dt * u, y = 0.f;
            #pragma unroll
            for (int n = 0; n < 16; n++) {
                float dA = __expf(dt * A[n]);
                h[n] = dA * h[n] + du * row[8 + n];
                y += h[n] * row[24 + n];
            }
            y += u * Dd;
            ybuf[orig * 64 + tid] = f2b(y);
        }
    }
    __syncthreads();
    // ---- Phase B: forward + gate, write into z columns ----
    {
        float A[16], wdt[8];
        #pragma unroll
        for (int n = 0; n < 16; n++) A[n] = -__expf(Alog_f[d * 16 + n]);
        #pragma unroll
        for (int r = 0; r < 8; r++) wdt[r] = Wdt_f[d * 8 + r];
        float bd = bdt_f[d], Dd = D_f[d];
        float c0 = cw_f[d * 4], c1 = cw_f[d * 4 + 1], c2 = cw_f[d * 4 + 2], c3 = cw_f[d * 4 + 3];
        float cb = cb_f[d];
        const float* xrow = xdbl_f + (size_t)s * 256 * 40;
        float h[16];
        #pragma unroll
        for (int n = 0; n < 16; n++) h[n] = 0.f;
        float w0 = 0.f, w1 = 0.f, w2 = 0.f, w3 = 0.f;
        float xc0 = to_f(xcol[(size_t)(s * 256 + 0) * 512]);
        float xc1 = to_f(xcol[(size_t)(s * 256 + 1) * 512]);
        float z0 = to_f(zcol[(size_t)(s * 256 + 0) * 512]);
        float z1 = to_f(zcol[(size_t)(s * 256 + 1) * 512]);
        for (int t = 0; t < 256; t++) {
            float xc = xc0; xc0 = xc1;
            float z  = z0;  z0  = z1;
            if (t + 2 < 256) {
                xc1 = to_f(xcol[(size_t)(s * 256 + t + 2) * 512]);
                z1  = to_f(zcol[(size_t)(s * 256 + t + 2) * 512]);
            }
            const float* row = xrow + t * 40;
            w0 = w1; w1 = w2; w2 = w3; w3 = xc;
            float u = silu_f(cb + c0 * w0 + c1 * w1 + c2 * w2 + c3 * w3);
            float dtr = bd;
            #pragma unroll
            for (int r = 0; r < 8; r++) dtr += row[r] * wdt[r];
            float dt = softplus_f(dtr);
            float du = dt * u, y = 0.f;
            #pragma unroll
            for (int n = 0; n < 16; n++) {
                float dA = __expf(dt * A[n]);
                h[n] = dA * h[n] + du * row[8 + n];
                y += h[n] * row[24 + n];
            }
            y += u * Dd;
            float yb = to_f(ybuf[t * 64 + tid]);
            xz[(size_t)(s * 256 + t) * 512 + 256 + d] = f2b((y + yb) * silu_f(z));
        }
    }
}

extern "C" void kernel_launch(void* const* d_in, const int* in_sizes, int n_in,
                              void* d_out, int out_size, void* d_ws, size_t ws_size,
                              hipStream_t stream) {
    const float* x      = (const float*)d_in[0];
    const float* g1     = (const float*)d_in[1];
    const float* b1     = (const float*)d_in[2];
    const float* W_in   = (const float*)d_in[3];
    const float* conv_w = (const float*)d_in[4];
    const float* conv_b = (const float*)d_in[5];
    const float* Wx     = (const float*)d_in[6];
    const float* Wdt    = (const float*)d_in[7];
    const float* bdt    = (const float*)d_in[8];
    const float* A_log  = (const float*)d_in[9];
    const float* Dvec   = (const float*)d_in[10];
    const float* conv_wb= (const float*)d_in[11];
    const float* conv_bb= (const float*)d_in[12];
    const float* Wxb    = (const float*)d_in[13];
    const float* Wdtb   = (const float*)d_in[14];
    const float* bdtb   = (const float*)d_in[15];
    const float* A_b_log= (const float*)d_in[16];
    const float* D_b    = (const float*)d_in[17];
    const float* W_out  = (const float*)d_in[18];
    const float* g2     = (const float*)d_in[19];
    const float* b2     = (const float*)d_in[20];
    const float* g3     = (const float*)d_in[21];
    const float* b3     = (const float*)d_in[22];
    const float* W1m    = (const float*)d_in[23];
    const float* b1m    = (const float*)d_in[24];
    const float* W2m    = (const float*)d_in[25];
    const float* b2m    = (const float*)d_in[26];

    // Workspace: 64 MiB of bf16 intermediates.
    bf16* ws  = (bf16*)d_ws;
    bf16* XZ  = ws;                    // [ROWS][512] bf16 = 64 MiB
    bf16* H2  = ws;                    // overlay after scans: [ROWS][128] = 16 MiB
    bf16* HID = ws + 8388608UL;        // [ROWS][256] = 32 MiB (ends at 48 MiB)
    float* out = (float*)d_out;        // 8,388,608 fp32 = 32 MiB
    // d_out as scratch (dead before the real fp32 write of d_out):
    bf16*  LN1OUT = (bf16*)d_out;      // [ROWS][128] bf16 = 16 MiB (dead after W_in GEMM)
    float* XDBL_F = (float*)d_out;     // [ROWS][40] fp32 = 10.5 MiB
    float* XDBL_B = (float*)d_out + 2621440UL;  // 10.5..21 MiB (< 32 MiB)

    // 1. LN1 -> d_out scratch (bf16)
    ln1_kernel<<<ROWS / 4, 256, 0, stream>>>(x, g1, b1, LN1OUT);
    // 2. XZ = LN1OUT @ W_in.T  [65536 x 512]  (MFMA)
    mfma_gemm_kernel<true, 0, 4><<<dim3(ROWS / 64, 8), 256, 0, stream>>>(
        LN1OUT, CC, W_in, nullptr, XZ, 512, 512, CC);
    // 3. xdbl (fwd/bwd) with fused conv+SiLU A-staging -> d_out scratch (fp32)
    gemm_conv_kernel<0><<<ROWS / 64, 256, 0, stream>>>(XZ, conv_w, conv_b, Wx, XDBL_F);
    gemm_conv_kernel<1><<<ROWS / 64, 256, 0, stream>>>(XZ, conv_wb, conv_bb, Wxb, XDBL_B);
    // 4. dual scan: backward y_b -> LDS, forward + gate -> z-columns of XZ in place
    scan_dual_kernel<<<SSEQ * 4, 64, 0, stream>>>(XZ, XDBL_F, XDBL_B,
        conv_w, conv_b, Wdt, bdt, A_log, Dvec,
        conv_wb, conv_bb, Wdtb, bdtb, A_b_log, D_b);
    // 5. yproj = gated_sum @ W_out.T, fused LN2 + residual -> d_out fp32 (MFMA)
    mfma_ln2res_kernel<<<ROWS / 64, 256, 0, stream>>>(XZ, W_out, g2, b2, x, out);
    // 6. H2 = LN3(xo) -> ws (XZ dead)
    ln3_kernel<<<ROWS / 4, 256, 0, stream>>>(out, g3, b3, H2);
    // 7. HID = gelu(H2 @ W1m + b1m)  [65536 x 256]  (MFMA)
    mfma_gemm_kernel<false, 1, 4><<<dim3(ROWS / 64, 4), 256, 0, stream>>>(
        H2, CC, W1m, b1m, HID, 2 * CC, 2 * CC, CC);
    // 8. d_out += HID @ W2m + b2m  (MFMA, fp32 accumulate)
    mfma_gemm_kernel<false, 2, 8><<<dim3(ROWS / 64, 2), 256, 0, stream>>>(
        HID, 2 * CC, W2m, b2m, out, CC, CC, 2 * CC);
}

// Round 7
// 712.995 us; speedup vs baseline: 1.3901x; 1.3901x over previous
//
#include <hip/hip_runtime.h>
#include <hip/hip_bf16.h>
#include <math.h>

// Problem dims
#define CC 128          // C
#define DI 256          // D_INNER
#define SSEQ 256        // B*N sequences
#define ROWS 65536      // SSEQ*TT

typedef __hip_bfloat16 bf16;
typedef __attribute__((ext_vector_type(8))) short short8;   // 8 bf16 (4 VGPRs) MFMA A/B frag
typedef __attribute__((ext_vector_type(4))) float float4v;  // MFMA C/D frag

__device__ __forceinline__ float to_f(float v) { return v; }
__device__ __forceinline__ float to_f(bf16 v)  { return __bfloat162float(v); }
__device__ __forceinline__ bf16  f2b(float v)  { return __float2bfloat16(v); }
__device__ __forceinline__ float bf2f_bits(short v) {
    union { unsigned u; float f; } c; c.u = ((unsigned)(unsigned short)v) << 16; return c.f;
}

__device__ __forceinline__ float wave_sum(float v) {
    #pragma unroll
    for (int o = 1; o < 64; o <<= 1) v += __shfl_xor(v, o, 64);
    return v;
}
__device__ __forceinline__ float silu_f(float x) { return x / (1.f + __expf(-x)); }
__device__ __forceinline__ float gelu_f(float x) { return 0.5f * x * (1.f + erff(x * 0.70710678118654752f)); }
__device__ __forceinline__ float softplus_f(float x) {
    return (x > 20.f) ? x : __logf(1.f + __expf(x));
}

// ---------------- LN1: x (B,T,N,C) fp32 -> bf16 rows in (s,t) order, s = b*64+n ----------------
__global__ __launch_bounds__(256) void ln1_kernel(const float* __restrict__ x,
                                                  const float* __restrict__ g,
                                                  const float* __restrict__ b,
                                                  bf16* __restrict__ out) {
    int wave = threadIdx.x >> 6, lane = threadIdx.x & 63;
    int r = blockIdx.x * 4 + wave;
    int s = r >> 8, t = r & 255;
    int bb = s >> 6, n = s & 63;
    size_t xbase = (((size_t)(bb * 256 + t)) * 64 + n) * CC;
    float v0 = x[xbase + lane], v1 = x[xbase + lane + 64];
    float s1 = wave_sum(v0 + v1);
    float s2 = wave_sum(v0 * v0 + v1 * v1);
    float m = s1 * (1.f / 128.f);
    float var = s2 * (1.f / 128.f) - m * m;
    float rstd = rsqrtf(var + 1e-5f);
    size_t ob = (size_t)r * CC;
    out[ob + lane]      = f2b((v0 - m) * rstd * g[lane]      + b[lane]);
    out[ob + lane + 64] = f2b((v1 - m) * rstd * g[lane + 64] + b[lane + 64]);
}

// ---------------- LN3: fp32 row-major in -> bf16 out ----------------
__global__ __launch_bounds__(256) void ln3_kernel(const float* __restrict__ in,
                                                  const float* __restrict__ g,
                                                  const float* __restrict__ b,
                                                  bf16* __restrict__ out) {
    int wave = threadIdx.x >> 6, lane = threadIdx.x & 63;
    int r = blockIdx.x * 4 + wave;
    size_t ib = (size_t)r * CC;
    float v0 = in[ib + lane], v1 = in[ib + lane + 64];
    float s1 = wave_sum(v0 + v1);
    float s2 = wave_sum(v0 * v0 + v1 * v1);
    float m = s1 * (1.f / 128.f);
    float var = s2 * (1.f / 128.f) - m * m;
    float rstd = rsqrtf(var + 1e-5f);
    out[ib + lane]      = f2b((v0 - m) * rstd * g[lane]      + b[lane]);
    out[ib + lane + 64] = f2b((v1 - m) * rstd * g[lane + 64] + b[lane + 64]);
}

// ================= MFMA GEMM, 64x64 tile, 256 threads (4 waves) =================
template <bool BTR, int EPI, int KTILES>
__global__ __launch_bounds__(256) void mfma_gemm_kernel(const bf16* __restrict__ A, int lda,
                                                        const float* __restrict__ B,
                                                        const float* __restrict__ bias,
                                                        void* __restrict__ Cout, int ldc,
                                                        int N, int K) {
    __shared__ bf16 As[64][40];
    __shared__ bf16 Bs[64][40];
    int tid = threadIdx.x;
    int m0 = blockIdx.x * 64;
    int n0 = blockIdx.y * 64;
    int wv = tid >> 6, lane = tid & 63;
    int lrow = lane & 15, quad = lane >> 4;
    int lk = quad * 8;
    float4v acc[4] = {};
    #pragma unroll
    for (int kt = 0; kt < KTILES; kt++) {
        int k0 = kt * 32;
        {
            int m = tid >> 2, part = tid & 3;
            uint4 v = *(const uint4*)(A + (size_t)(m0 + m) * lda + k0 + part * 8);
            *(uint4*)&As[m][part * 8] = v;
        }
        if (BTR) {
            int n = tid >> 2, part = tid & 3;
            const float* src = B + (size_t)(n0 + n) * K + k0 + part * 8;
            bf16 tmp[8];
            #pragma unroll
            for (int j = 0; j < 8; j++) tmp[j] = f2b(src[j]);
            *(uint4*)&Bs[n][part * 8] = *(uint4*)tmp;
        } else {
            int kk = tid >> 3, nf = (tid & 7) * 8;
            const float* src = B + (size_t)(k0 + kk) * N + n0 + nf;
            #pragma unroll
            for (int j = 0; j < 8; j++) Bs[nf + j][kk] = f2b(src[j]);
        }
        __syncthreads();
        short8 a = *(const short8*)&As[wv * 16 + lrow][lk];
        #pragma unroll
        for (int jt = 0; jt < 4; jt++) {
            short8 bfr = *(const short8*)&Bs[jt * 16 + lrow][lk];
            acc[jt] = __builtin_amdgcn_mfma_f32_16x16x32_bf16(a, bfr, acc[jt], 0, 0, 0);
        }
        __syncthreads();
    }
    #pragma unroll
    for (int jt = 0; jt < 4; jt++) {
        int col = n0 + jt * 16 + lrow;
        float bs = (EPI >= 1) ? bias[col] : 0.f;
        #pragma unroll
        for (int r = 0; r < 4; r++) {
            int row = m0 + wv * 16 + quad * 4 + r;
            float v = acc[jt][r] + bs;
            if (EPI == 1) v = gelu_f(v);
            if (EPI == 2) {
                float* Cf = (float*)Cout;
                Cf[(size_t)row * ldc + col] += v;
            } else {
                bf16* Cb = (bf16*)Cout;
                Cb[(size_t)row * ldc + col] = f2b(v);
            }
        }
    }
}

// ======== MFMA W_out GEMM (64x128 tile), A = YF+YB, fused LN2 + residual epilogue ========
__global__ __launch_bounds__(256) void mfma_ln2res_kernel(const bf16* __restrict__ YF,
                                                          const bf16* __restrict__ YB,
                                                          const float* __restrict__ Wout,
                                                          const float* __restrict__ g,
                                                          const float* __restrict__ b,
                                                          const float* __restrict__ x,
                                                          float* __restrict__ out) {
    __shared__ bf16 As[64][40];
    __shared__ bf16 Bs[128][40];
    int tid = threadIdx.x;
    int m0 = blockIdx.x * 64;
    int wv = tid >> 6, lane = tid & 63;
    int lrow = lane & 15, quad = lane >> 4;
    int lk = quad * 8;
    float4v acc[8] = {};
    #pragma unroll
    for (int kt = 0; kt < 8; kt++) {          // K = 256
        int k0 = kt * 32;
        {
            int m = tid >> 2, part = tid & 3;
            size_t off = (size_t)(m0 + m) * 256 + k0 + part * 8;
            short8 vf = *(const short8*)(YF + off);
            short8 vb = *(const short8*)(YB + off);
            bf16 tmp[8];
            #pragma unroll
            for (int j = 0; j < 8; j++) tmp[j] = f2b(bf2f_bits(vf[j]) + bf2f_bits(vb[j]));
            *(uint4*)&As[m][part * 8] = *(uint4*)tmp;
        }
        #pragma unroll
        for (int it = 0; it < 2; it++) {
            int idx = tid + it * 256;
            int n = idx >> 2, part = idx & 3;
            const float* src = Wout + (size_t)n * 256 + k0 + part * 8;
            bf16 tmp[8];
            #pragma unroll
            for (int j = 0; j < 8; j++) tmp[j] = f2b(src[j]);
            *(uint4*)&Bs[n][part * 8] = *(uint4*)tmp;
        }
        __syncthreads();
        short8 a = *(const short8*)&As[wv * 16 + lrow][lk];
        #pragma unroll
        for (int jt = 0; jt < 8; jt++) {
            short8 bfr = *(const short8*)&Bs[jt * 16 + lrow][lk];
            acc[jt] = __builtin_amdgcn_mfma_f32_16x16x32_bf16(a, bfr, acc[jt], 0, 0, 0);
        }
        __syncthreads();
    }
    #pragma unroll
    for (int r = 0; r < 4; r++) {
        float ps = 0.f, ps2 = 0.f;
        #pragma unroll
        for (int jt = 0; jt < 8; jt++) { float v = acc[jt][r]; ps += v; ps2 += v * v; }
        #pragma unroll
        for (int o = 1; o < 16; o <<= 1) {
            ps  += __shfl_xor(ps, o, 64);
            ps2 += __shfl_xor(ps2, o, 64);
        }
        float m = ps * (1.f / 128.f);
        float var = ps2 * (1.f / 128.f) - m * m;
        float rstd = rsqrtf(var + 1e-5f);
        int row = m0 + wv * 16 + quad * 4 + r;
        int s = row >> 8, t = row & 255;
        int bb = s >> 6, n = s & 63;
        size_t xbase = (((size_t)(bb * 256 + t)) * 64 + n) * CC;
        #pragma unroll
        for (int jt = 0; jt < 8; jt++) {
            int col = jt * 16 + lrow;
            out[xbase + col] = (acc[jt][r] - m) * rstd * g[col] + b[col] + x[xbase + col];
        }
    }
}

// ---------------- xdbl GEMM with fused causal conv + SiLU A-staging (VALU, N=40, bf16 out) ----------------
template <int DIR>
__global__ __launch_bounds__(256) void gemm_conv_kernel(const bf16* __restrict__ xz,
                                                        const float* __restrict__ cw,
                                                        const float* __restrict__ cb,
                                                        const float* __restrict__ B,
                                                        bf16* __restrict__ C) {
    __shared__ float As[16][65];
    __shared__ float Bs[16][65];
    int tid = threadIdx.x;
    int m0 = blockIdx.x * 64;
    int tx = tid & 15, ty = tid >> 4;
    float acc[4][4] = {};
    for (int k0 = 0; k0 < 256; k0 += 16) {
        #pragma unroll
        for (int r = 0; r < 4; r++) {
            int idx = tid + r * 256;
            int m = idx >> 4, kk = idx & 15;
            int row = m0 + m;
            int t = row & 255, s = row >> 8;
            int d = k0 + kk;
            float a = cb[d];
            #pragma unroll
            for (int j = 0; j < 4; j++) {
                int tj = t - 3 + j;
                if (tj >= 0) {
                    int src = DIR ? (255 - tj) : tj;
                    a += cw[d * 4 + j] * to_f(xz[(size_t)(s * 256 + src) * 512 + d]);
                }
            }
            As[kk][m] = silu_f(a);
        }
        #pragma unroll
        for (int r = 0; r < 4; r++) {
            int idx = tid + r * 256;
            int n = idx >> 4, kk = idx & 15;
            Bs[kk][n] = (n < 40) ? B[(size_t)n * 256 + k0 + kk] : 0.f;
        }
        __syncthreads();
        #pragma unroll
        for (int k = 0; k < 16; k++) {
            float a[4], bv[4];
            #pragma unroll
            for (int i = 0; i < 4; i++) a[i] = As[k][ty * 4 + i];
            #pragma unroll
            for (int j = 0; j < 4; j++) bv[j] = Bs[k][tx * 4 + j];
            #pragma unroll
            for (int i = 0; i < 4; i++)
                #pragma unroll
                for (int j = 0; j < 4; j++) acc[i][j] += a[i] * bv[j];
        }
        __syncthreads();
    }
    #pragma unroll
    for (int i = 0; i < 4; i++) {
        int row = m0 + ty * 4 + i;
        #pragma unroll
        for (int j = 0; j < 4; j++) {
            int col = tx * 4 + j;
            if (col < 40) C[(size_t)row * 40 + col] = f2b(acc[i][j]);
        }
    }
}

// ---------------- Direction-parallel selective scan ----------------
// Grid 2048: blockIdx = dir*1024 + s*4 + q.  64 threads, d = q*64+tid.
// Whole sequence's xdbl (256 rows x 40 bf16 = 20 KB) staged to LDS once (coalesced).
// Each direction writes its own gated product y_dir*silu(z) to YF/YB;
// downstream W_out GEMM stages A = YF+YB.
__global__ __launch_bounds__(64) void scan_kernel(const bf16* __restrict__ xz,
        const bf16* __restrict__ xdbl_f, const bf16* __restrict__ xdbl_b,
        const float* __restrict__ cw_f, const float* __restrict__ cb_f,
        const float* __restrict__ Wdt_f, const float* __restrict__ bdt_f,
        const float* __restrict__ Alog_f, const float* __restrict__ D_f,
        const float* __restrict__ cw_b, const float* __restrict__ cb_b,
        const float* __restrict__ Wdt_b, const float* __restrict__ bdt_b,
        const float* __restrict__ Alog_b, const float* __restrict__ D_b,
        bf16* __restrict__ YF, bf16* __restrict__ YB) {
    __shared__ bf16 rows[256 * 40];   // 20 KB
    int tid = threadIdx.x;
    int dir = blockIdx.x >> 10;
    int rem = blockIdx.x & 1023;
    int s = rem >> 2, q = rem & 3;
    int d = q * 64 + tid;

    // ---- stage xdbl for this (sequence, direction): 1280 uint4, coalesced ----
    const bf16* xd = (dir ? xdbl_b : xdbl_f) + (size_t)s * 10240;
    #pragma unroll
    for (int i = 0; i < 20; i++)
        ((uint4*)rows)[i * 64 + tid] = ((const uint4*)xd)[i * 64 + tid];

    // ---- per-thread params (direction-selected) ----
    const float* Alog = dir ? Alog_b : Alog_f;
    const float* Wdt  = dir ? Wdt_b  : Wdt_f;
    const float* cwp  = dir ? cw_b   : cw_f;
    float A[16], wdt[8];
    #pragma unroll
    for (int n = 0; n < 16; n++) A[n] = -__expf(Alog[d * 16 + n]);
    #pragma unroll
    for (int r = 0; r < 8; r++) wdt[r] = Wdt[d * 8 + r];
    float bd = dir ? bdt_b[d] : bdt_f[d];
    float Dd = dir ? D_b[d]   : D_f[d];
    float cb = dir ? cb_b[d]  : cb_f[d];
    float c0 = cwp[d * 4], c1 = cwp[d * 4 + 1], c2 = cwp[d * 4 + 2], c3 = cwp[d * 4 + 3];
    bf16* Y = dir ? YB : YF;
    const bf16* xcol = xz + d;
    const bf16* zcol = xz + 256 + d;
    __syncthreads();

    float h[16];
    #pragma unroll
    for (int n = 0; n < 16; n++) h[n] = 0.f;
    float w0 = 0.f, w1 = 0.f, w2 = 0.f, w3 = 0.f;
    // distance-2 prefetch: original-time index for scan step t is (dir ? 255-t : t)
    int o0 = dir ? 255 : 0, o1 = dir ? 254 : 1;
    float xc0 = to_f(xcol[(size_t)(s * 256 + o0) * 512]);
    float xc1 = to_f(xcol[(size_t)(s * 256 + o1) * 512]);
    float z0  = to_f(zcol[(size_t)(s * 256 + o0) * 512]);
    float z1  = to_f(zcol[(size_t)(s * 256 + o1) * 512]);
    for (int t = 0; t < 256; t++) {
        int tt = dir ? (255 - t) : t;
        float xc = xc0; xc0 = xc1;
        float z  = z0;  z0  = z1;
        if (t + 2 < 256) {
            int onx = dir ? (253 - t) : (t + 2);
            xc1 = to_f(xcol[(size_t)(s * 256 + onx) * 512]);
            z1  = to_f(zcol[(size_t)(s * 256 + onx) * 512]);
        }
        const bf16* row = rows + t * 40;
        short8 r0 = *(const short8*)(row);        // dt inputs 0-7
        short8 r1 = *(const short8*)(row + 8);    // B 0-7
        short8 r2 = *(const short8*)(row + 16);   // B 8-15
        short8 r3 = *(const short8*)(row + 24);   // C 0-7
        short8 r4 = *(const short8*)(row + 32);   // C 8-15
        w0 = w1; w1 = w2; w2 = w3; w3 = xc;
        float u = silu_f(cb + c0 * w0 + c1 * w1 + c2 * w2 + c3 * w3);
        float dtr = bd;
        #pragma unroll
        for (int r = 0; r < 8; r++) dtr += bf2f_bits(r0[r]) * wdt[r];
        float dt = softplus_f(dtr);
        float du = dt * u, y = 0.f;
        #pragma unroll
        for (int n = 0; n < 8; n++) {
            float dA = __expf(dt * A[n]);
            h[n] = dA * h[n] + du * bf2f_bits(r1[n]);
            y += h[n] * bf2f_bits(r3[n]);
        }
        #pragma unroll
        for (int n = 8; n < 16; n++) {
            float dA = __expf(dt * A[n]);
            h[n] = dA * h[n] + du * bf2f_bits(r2[n - 8]);
            y += h[n] * bf2f_bits(r4[n - 8]);
        }
        y += u * Dd;
        Y[(size_t)(s * 256 + tt) * 256 + d] = f2b(y * silu_f(z));
    }
}

extern "C" void kernel_launch(void* const* d_in, const int* in_sizes, int n_in,
                              void* d_out, int out_size, void* d_ws, size_t ws_size,
                              hipStream_t stream) {
    const float* x      = (const float*)d_in[0];
    const float* g1     = (const float*)d_in[1];
    const float* b1     = (const float*)d_in[2];
    const float* W_in   = (const float*)d_in[3];
    const float* conv_w = (const float*)d_in[4];
    const float* conv_b = (const float*)d_in[5];
    const float* Wx     = (const float*)d_in[6];
    const float* Wdt    = (const float*)d_in[7];
    const float* bdt    = (const float*)d_in[8];
    const float* A_log  = (const float*)d_in[9];
    const float* Dvec   = (const float*)d_in[10];
    const float* conv_wb= (const float*)d_in[11];
    const float* conv_bb= (const float*)d_in[12];
    const float* Wxb    = (const float*)d_in[13];
    const float* Wdtb   = (const float*)d_in[14];
    const float* bdtb   = (const float*)d_in[15];
    const float* A_b_log= (const float*)d_in[16];
    const float* D_b    = (const float*)d_in[17];
    const float* W_out  = (const float*)d_in[18];
    const float* g2     = (const float*)d_in[19];
    const float* b2     = (const float*)d_in[20];
    const float* g3     = (const float*)d_in[21];
    const float* b3     = (const float*)d_in[22];
    const float* W1m    = (const float*)d_in[23];
    const float* b1m    = (const float*)d_in[24];
    const float* W2m    = (const float*)d_in[25];
    const float* b2m    = (const float*)d_in[26];

    // Workspace: 128 MiB of bf16 intermediates (128 MiB footprint ran clean in round 2).
    bf16* ws  = (bf16*)d_ws;
    bf16* XZ  = ws;                    // [ROWS][512] bf16 = 64 MiB  [0, 64M)
    bf16* YF  = ws + 33554432UL;       // [ROWS][256] bf16 = 32 MiB  [64M, 96M)
    bf16* YB  = ws + 50331648UL;       // [ROWS][256] bf16 = 32 MiB  [96M, 128M)
    bf16* H2  = ws;                    // overlay (XZ dead after scan): 16 MiB
    bf16* HID = ws + 8388608UL;        // overlay: [16M, 48M)
    float* out = (float*)d_out;        // 8,388,608 fp32 = 32 MiB
    // d_out as scratch (dead before the real fp32 write of d_out):
    bf16* LN1OUT = (bf16*)d_out;       // [ROWS][128] bf16 = 16 MiB (dead after W_in GEMM)
    bf16* XDBL_F = (bf16*)d_out;       // [ROWS][40] bf16 = 5.24 MiB
    bf16* XDBL_B = (bf16*)d_out + 2621440UL;   // ends at 10.5 MiB

    // 1. LN1 -> d_out scratch (bf16)
    ln1_kernel<<<ROWS / 4, 256, 0, stream>>>(x, g1, b1, LN1OUT);
    // 2. XZ = LN1OUT @ W_in.T  [65536 x 512]  (MFMA)
    mfma_gemm_kernel<true, 0, 4><<<dim3(ROWS / 64, 8), 256, 0, stream>>>(
        LN1OUT, CC, W_in, nullptr, XZ, 512, 512, CC);
    // 3. xdbl (fwd/bwd) with fused conv+SiLU A-staging -> d_out scratch (bf16)
    gemm_conv_kernel<0><<<ROWS / 64, 256, 0, stream>>>(XZ, conv_w, conv_b, Wx, XDBL_F);
    gemm_conv_kernel<1><<<ROWS / 64, 256, 0, stream>>>(XZ, conv_wb, conv_bb, Wxb, XDBL_B);
    // 4. direction-parallel scan -> YF, YB (gated per-direction products)
    scan_kernel<<<2048, 64, 0, stream>>>(XZ, XDBL_F, XDBL_B,
        conv_w, conv_b, Wdt, bdt, A_log, Dvec,
        conv_wb, conv_bb, Wdtb, bdtb, A_b_log, D_b, YF, YB);
    // 5. yproj = (YF+YB) @ W_out.T, fused LN2 + residual -> d_out fp32 (MFMA)
    mfma_ln2res_kernel<<<ROWS / 64, 256, 0, stream>>>(YF, YB, W_out, g2, b2, x, out);
    // 6. H2 = LN3(xo) -> ws (XZ dead)
    ln3_kernel<<<ROWS / 4, 256, 0, stream>>>(out, g3, b3, H2);
    // 7. HID = gelu(H2 @ W1m + b1m)  [65536 x 256]  (MFMA)
    mfma_gemm_kernel<false, 1, 4><<<dim3(ROWS / 64, 4), 256, 0, stream>>>(
        H2, CC, W1m, b1m, HID, 2 * CC, 2 * CC, CC);
    // 8. d_out += HID @ W2m + b2m  (MFMA, fp32 accumulate)
    mfma_gemm_kernel<false, 2, 8><<<dim3(ROWS / 64, 2), 256, 0, stream>>>(
        HID, 2 * CC, W2m, b2m, out, CC, CC, 2 * CC);
}

// Round 8
// 652.261 us; speedup vs baseline: 1.5195x; 1.0931x over previous
//
#include <hip/hip_runtime.h>
#include <hip/hip_bf16.h>
#include <math.h>

// Problem dims
#define CC 128          // C
#define DI 256          // D_INNER
#define SSEQ 256        // B*N sequences
#define ROWS 65536      // SSEQ*TT

typedef __hip_bfloat16 bf16;
typedef __attribute__((ext_vector_type(8))) short short8;   // 8 bf16 (4 VGPRs) MFMA A/B frag
typedef __attribute__((ext_vector_type(4))) float float4v;  // MFMA C/D frag

__device__ __forceinline__ float to_f(float v) { return v; }
__device__ __forceinline__ float to_f(bf16 v)  { return __bfloat162float(v); }
__device__ __forceinline__ bf16  f2b(float v)  { return __float2bfloat16(v); }
__device__ __forceinline__ float bf2f_bits(short v) {
    union { unsigned u; float f; } c; c.u = ((unsigned)(unsigned short)v) << 16; return c.f;
}

__device__ __forceinline__ float wave_sum(float v) {
    #pragma unroll
    for (int o = 1; o < 64; o <<= 1) v += __shfl_xor(v, o, 64);
    return v;
}
__device__ __forceinline__ float silu_f(float x) {
    return x * __builtin_amdgcn_rcpf(1.f + __expf(-x));
}
__device__ __forceinline__ float gelu_f(float x) { return 0.5f * x * (1.f + erff(x * 0.70710678118654752f)); }
__device__ __forceinline__ float softplus_f(float x) {
    return (x > 20.f) ? x : __logf(1.f + __expf(x));
}

// ---------------- LN1: x (B,T,N,C) fp32 -> bf16 rows in (s,t) order, s = b*64+n ----------------
__global__ __launch_bounds__(256) void ln1_kernel(const float* __restrict__ x,
                                                  const float* __restrict__ g,
                                                  const float* __restrict__ b,
                                                  bf16* __restrict__ out) {
    int wave = threadIdx.x >> 6, lane = threadIdx.x & 63;
    int r = blockIdx.x * 4 + wave;
    int s = r >> 8, t = r & 255;
    int bb = s >> 6, n = s & 63;
    size_t xbase = (((size_t)(bb * 256 + t)) * 64 + n) * CC;
    float v0 = x[xbase + lane], v1 = x[xbase + lane + 64];
    float s1 = wave_sum(v0 + v1);
    float s2 = wave_sum(v0 * v0 + v1 * v1);
    float m = s1 * (1.f / 128.f);
    float var = s2 * (1.f / 128.f) - m * m;
    float rstd = rsqrtf(var + 1e-5f);
    size_t ob = (size_t)r * CC;
    out[ob + lane]      = f2b((v0 - m) * rstd * g[lane]      + b[lane]);
    out[ob + lane + 64] = f2b((v1 - m) * rstd * g[lane + 64] + b[lane + 64]);
}

// ---------------- LN3: fp32 row-major in -> bf16 out ----------------
__global__ __launch_bounds__(256) void ln3_kernel(const float* __restrict__ in,
                                                  const float* __restrict__ g,
                                                  const float* __restrict__ b,
                                                  bf16* __restrict__ out) {
    int wave = threadIdx.x >> 6, lane = threadIdx.x & 63;
    int r = blockIdx.x * 4 + wave;
    size_t ib = (size_t)r * CC;
    float v0 = in[ib + lane], v1 = in[ib + lane + 64];
    float s1 = wave_sum(v0 + v1);
    float s2 = wave_sum(v0 * v0 + v1 * v1);
    float m = s1 * (1.f / 128.f);
    float var = s2 * (1.f / 128.f) - m * m;
    float rstd = rsqrtf(var + 1e-5f);
    out[ib + lane]      = f2b((v0 - m) * rstd * g[lane]      + b[lane]);
    out[ib + lane + 64] = f2b((v1 - m) * rstd * g[lane + 64] + b[lane + 64]);
}

// ================= MFMA GEMM, 64x64 tile, 256 threads (4 waves) =================
template <bool BTR, int EPI, int KTILES>
__global__ __launch_bounds__(256) void mfma_gemm_kernel(const bf16* __restrict__ A, int lda,
                                                        const float* __restrict__ B,
                                                        const float* __restrict__ bias,
                                                        void* __restrict__ Cout, int ldc,
                                                        int N, int K) {
    __shared__ bf16 As[64][40];
    __shared__ bf16 Bs[64][40];
    int tid = threadIdx.x;
    int m0 = blockIdx.x * 64;
    int n0 = blockIdx.y * 64;
    int wv = tid >> 6, lane = tid & 63;
    int lrow = lane & 15, quad = lane >> 4;
    int lk = quad * 8;
    float4v acc[4] = {};
    #pragma unroll
    for (int kt = 0; kt < KTILES; kt++) {
        int k0 = kt * 32;
        {
            int m = tid >> 2, part = tid & 3;
            uint4 v = *(const uint4*)(A + (size_t)(m0 + m) * lda + k0 + part * 8);
            *(uint4*)&As[m][part * 8] = v;
        }
        if (BTR) {
            int n = tid >> 2, part = tid & 3;
            const float* src = B + (size_t)(n0 + n) * K + k0 + part * 8;
            bf16 tmp[8];
            #pragma unroll
            for (int j = 0; j < 8; j++) tmp[j] = f2b(src[j]);
            *(uint4*)&Bs[n][part * 8] = *(uint4*)tmp;
        } else {
            int kk = tid >> 3, nf = (tid & 7) * 8;
            const float* src = B + (size_t)(k0 + kk) * N + n0 + nf;
            #pragma unroll
            for (int j = 0; j < 8; j++) Bs[nf + j][kk] = f2b(src[j]);
        }
        __syncthreads();
        short8 a = *(const short8*)&As[wv * 16 + lrow][lk];
        #pragma unroll
        for (int jt = 0; jt < 4; jt++) {
            short8 bfr = *(const short8*)&Bs[jt * 16 + lrow][lk];
            acc[jt] = __builtin_amdgcn_mfma_f32_16x16x32_bf16(a, bfr, acc[jt], 0, 0, 0);
        }
        __syncthreads();
    }
    #pragma unroll
    for (int jt = 0; jt < 4; jt++) {
        int col = n0 + jt * 16 + lrow;
        float bs = (EPI >= 1) ? bias[col] : 0.f;
        #pragma unroll
        for (int r = 0; r < 4; r++) {
            int row = m0 + wv * 16 + quad * 4 + r;
            float v = acc[jt][r] + bs;
            if (EPI == 1) v = gelu_f(v);
            if (EPI == 2) {
                float* Cf = (float*)Cout;
                Cf[(size_t)row * ldc + col] += v;
            } else {
                bf16* Cb = (bf16*)Cout;
                Cb[(size_t)row * ldc + col] = f2b(v);
            }
        }
    }
}

// ======== MFMA W_out GEMM (64x128 tile), A = (YF+YB)*silu(z), fused LN2 + residual ========
__global__ __launch_bounds__(256) void mfma_ln2res_kernel(const bf16* __restrict__ YF,
                                                          const bf16* __restrict__ YB,
                                                          const bf16* __restrict__ xz,
                                                          const float* __restrict__ Wout,
                                                          const float* __restrict__ g,
                                                          const float* __restrict__ b,
                                                          const float* __restrict__ x,
                                                          float* __restrict__ out) {
    __shared__ bf16 As[64][40];
    __shared__ bf16 Bs[128][40];
    int tid = threadIdx.x;
    int m0 = blockIdx.x * 64;
    int wv = tid >> 6, lane = tid & 63;
    int lrow = lane & 15, quad = lane >> 4;
    int lk = quad * 8;
    float4v acc[8] = {};
    #pragma unroll
    for (int kt = 0; kt < 8; kt++) {          // K = 256
        int k0 = kt * 32;
        {
            int m = tid >> 2, part = tid & 3;
            size_t off = (size_t)(m0 + m) * 256 + k0 + part * 8;
            short8 vf = *(const short8*)(YF + off);
            short8 vb = *(const short8*)(YB + off);
            short8 vz = *(const short8*)(xz + (size_t)(m0 + m) * 512 + 256 + k0 + part * 8);
            bf16 tmp[8];
            #pragma unroll
            for (int j = 0; j < 8; j++)
                tmp[j] = f2b((bf2f_bits(vf[j]) + bf2f_bits(vb[j])) * silu_f(bf2f_bits(vz[j])));
            *(uint4*)&As[m][part * 8] = *(uint4*)tmp;
        }
        #pragma unroll
        for (int it = 0; it < 2; it++) {
            int idx = tid + it * 256;
            int n = idx >> 2, part = idx & 3;
            const float* src = Wout + (size_t)n * 256 + k0 + part * 8;
            bf16 tmp[8];
            #pragma unroll
            for (int j = 0; j < 8; j++) tmp[j] = f2b(src[j]);
            *(uint4*)&Bs[n][part * 8] = *(uint4*)tmp;
        }
        __syncthreads();
        short8 a = *(const short8*)&As[wv * 16 + lrow][lk];
        #pragma unroll
        for (int jt = 0; jt < 8; jt++) {
            short8 bfr = *(const short8*)&Bs[jt * 16 + lrow][lk];
            acc[jt] = __builtin_amdgcn_mfma_f32_16x16x32_bf16(a, bfr, acc[jt], 0, 0, 0);
        }
        __syncthreads();
    }
    #pragma unroll
    for (int r = 0; r < 4; r++) {
        float ps = 0.f, ps2 = 0.f;
        #pragma unroll
        for (int jt = 0; jt < 8; jt++) { float v = acc[jt][r]; ps += v; ps2 += v * v; }
        #pragma unroll
        for (int o = 1; o < 16; o <<= 1) {
            ps  += __shfl_xor(ps, o, 64);
            ps2 += __shfl_xor(ps2, o, 64);
        }
        float m = ps * (1.f / 128.f);
        float var = ps2 * (1.f / 128.f) - m * m;
        float rstd = rsqrtf(var + 1e-5f);
        int row = m0 + wv * 16 + quad * 4 + r;
        int s = row >> 8, t = row & 255;
        int bb = s >> 6, n = s & 63;
        size_t xbase = (((size_t)(bb * 256 + t)) * 64 + n) * CC;
        #pragma unroll
        for (int jt = 0; jt < 8; jt++) {
            int col = jt * 16 + lrow;
            out[xbase + col] = (acc[jt][r] - m) * rstd * g[col] + b[col] + x[xbase + col];
        }
    }
}

// ---------------- xdbl GEMM with fused causal conv + SiLU A-staging (VALU, N=40, bf16 out) ----------------
template <int DIR>
__global__ __launch_bounds__(256) void gemm_conv_kernel(const bf16* __restrict__ xz,
                                                        const float* __restrict__ cw,
                                                        const float* __restrict__ cb,
                                                        const float* __restrict__ B,
                                                        bf16* __restrict__ C) {
    __shared__ float As[16][65];
    __shared__ float Bs[16][65];
    int tid = threadIdx.x;
    int m0 = blockIdx.x * 64;
    int tx = tid & 15, ty = tid >> 4;
    float acc[4][4] = {};
    for (int k0 = 0; k0 < 256; k0 += 16) {
        #pragma unroll
        for (int r = 0; r < 4; r++) {
            int idx = tid + r * 256;
            int m = idx >> 4, kk = idx & 15;
            int row = m0 + m;
            int t = row & 255, s = row >> 8;
            int d = k0 + kk;
            float a = cb[d];
            #pragma unroll
            for (int j = 0; j < 4; j++) {
                int tj = t - 3 + j;
                if (tj >= 0) {
                    int src = DIR ? (255 - tj) : tj;
                    a += cw[d * 4 + j] * to_f(xz[(size_t)(s * 256 + src) * 512 + d]);
                }
            }
            As[kk][m] = silu_f(a);
        }
        #pragma unroll
        for (int r = 0; r < 4; r++) {
            int idx = tid + r * 256;
            int n = idx >> 4, kk = idx & 15;
            Bs[kk][n] = (n < 40) ? B[(size_t)n * 256 + k0 + kk] : 0.f;
        }
        __syncthreads();
        #pragma unroll
        for (int k = 0; k < 16; k++) {
            float a[4], bv[4];
            #pragma unroll
            for (int i = 0; i < 4; i++) a[i] = As[k][ty * 4 + i];
            #pragma unroll
            for (int j = 0; j < 4; j++) bv[j] = Bs[k][tx * 4 + j];
            #pragma unroll
            for (int i = 0; i < 4; i++)
                #pragma unroll
                for (int j = 0; j < 4; j++) acc[i][j] += a[i] * bv[j];
        }
        __syncthreads();
    }
    #pragma unroll
    for (int i = 0; i < 4; i++) {
        int row = m0 + ty * 4 + i;
        #pragma unroll
        for (int j = 0; j < 4; j++) {
            int col = tx * 4 + j;
            if (col < 40) C[(size_t)row * 40 + col] = f2b(acc[i][j]);
        }
    }
}

// ---------------- Direction-parallel selective scan v3 ----------------
// Grid 512: blockIdx = dir*256 + s.  256 threads, d = tid.
// Whole sequence's xdbl staged to LDS as fp32 (256 rows x 40 = 40 KB) once.
// Per-step row reads are broadcast ds_read_b128 (no per-step unpack VALU).
// Writes RAW y (ungated) to YF/YB; the W_out GEMM applies (yf+yb)*silu(z).
__global__ __launch_bounds__(256) void scan_kernel(const bf16* __restrict__ xz,
        const bf16* __restrict__ xdbl_f, const bf16* __restrict__ xdbl_b,
        const float* __restrict__ cw_f, const float* __restrict__ cb_f,
        const float* __restrict__ Wdt_f, const float* __restrict__ bdt_f,
        const float* __restrict__ Alog_f, const float* __restrict__ D_f,
        const float* __restrict__ cw_b, const float* __restrict__ cb_b,
        const float* __restrict__ Wdt_b, const float* __restrict__ bdt_b,
        const float* __restrict__ Alog_b, const float* __restrict__ D_b,
        bf16* __restrict__ YF, bf16* __restrict__ YB) {
    __shared__ float rows[256 * 40];   // 40 KB fp32
    int tid = threadIdx.x;
    int dir = blockIdx.x >> 8;
    int s = blockIdx.x & 255;
    int d = tid;

    // ---- stage xdbl (bf16 -> fp32 LDS), 1280 uint4 reads, coalesced ----
    const bf16* xd = (dir ? xdbl_b : xdbl_f) + (size_t)s * 10240;
    #pragma unroll
    for (int i = 0; i < 5; i++) {
        int idx = i * 256 + tid;
        uint4 v = ((const uint4*)xd)[idx];
        short8 sv = *(short8*)&v;
        float f[8];
        #pragma unroll
        for (int j = 0; j < 8; j++) f[j] = bf2f_bits(sv[j]);
        *(float4*)&rows[idx * 8]     = *(float4*)&f[0];
        *(float4*)&rows[idx * 8 + 4] = *(float4*)&f[4];
    }

    // ---- per-thread params (direction-selected) ----
    const float* Alog = dir ? Alog_b : Alog_f;
    const float* Wdtp = dir ? Wdt_b  : Wdt_f;
    const float* cwp  = dir ? cw_b   : cw_f;
    float A[16], wdt[8];
    #pragma unroll
    for (int n = 0; n < 16; n++) A[n] = -__expf(Alog[d * 16 + n]);
    #pragma unroll
    for (int r = 0; r < 8; r++) wdt[r] = Wdtp[d * 8 + r];
    float bd = dir ? bdt_b[d] : bdt_f[d];
    float Dd = dir ? D_b[d]   : D_f[d];
    float cb = dir ? cb_b[d]  : cb_f[d];
    float c0 = cwp[d * 4], c1 = cwp[d * 4 + 1], c2 = cwp[d * 4 + 2], c3 = cwp[d * 4 + 3];
    bf16* Y = dir ? YB : YF;
    const bf16* xcol = xz + d;
    __syncthreads();

    float h[16];
    #pragma unroll
    for (int n = 0; n < 16; n++) h[n] = 0.f;
    float w0 = 0.f, w1 = 0.f, w2 = 0.f, w3 = 0.f;
    int o0 = dir ? 255 : 0, o1 = dir ? 254 : 1;
    float xc0 = to_f(xcol[(size_t)(s * 256 + o0) * 512]);
    float xc1 = to_f(xcol[(size_t)(s * 256 + o1) * 512]);
    for (int t = 0; t < 256; t++) {
        int tt = dir ? (255 - t) : t;
        float xc = xc0; xc0 = xc1;
        if (t + 2 < 256) {
            int onx = dir ? (253 - t) : (t + 2);
            xc1 = to_f(xcol[(size_t)(s * 256 + onx) * 512]);
        }
        const float* row = rows + t * 40;
        float4 q0 = *(const float4*)(row);        // dt inputs 0-3
        float4 q1 = *(const float4*)(row + 4);    // dt inputs 4-7
        float4 qb0 = *(const float4*)(row + 8);   // B 0-3
        float4 qb1 = *(const float4*)(row + 12);
        float4 qb2 = *(const float4*)(row + 16);
        float4 qb3 = *(const float4*)(row + 20);
        float4 qc0 = *(const float4*)(row + 24);  // C 0-3
        float4 qc1 = *(const float4*)(row + 28);
        float4 qc2 = *(const float4*)(row + 32);
        float4 qc3 = *(const float4*)(row + 36);
        w0 = w1; w1 = w2; w2 = w3; w3 = xc;
        float u = silu_f(cb + c0 * w0 + c1 * w1 + c2 * w2 + c3 * w3);
        float dtr = bd;
        dtr += q0.x * wdt[0] + q0.y * wdt[1] + q0.z * wdt[2] + q0.w * wdt[3];
        dtr += q1.x * wdt[4] + q1.y * wdt[5] + q1.z * wdt[6] + q1.w * wdt[7];
        float dt = softplus_f(dtr);
        float du = dt * u, y = 0.f;
        const float* Bv = (const float*)&qb0;     // contiguous qb0..qb3 on stack? avoid; unroll manually
        float Bm[16] = {qb0.x,qb0.y,qb0.z,qb0.w, qb1.x,qb1.y,qb1.z,qb1.w,
                        qb2.x,qb2.y,qb2.z,qb2.w, qb3.x,qb3.y,qb3.z,qb3.w};
        float Cm[16] = {qc0.x,qc0.y,qc0.z,qc0.w, qc1.x,qc1.y,qc1.z,qc1.w,
                        qc2.x,qc2.y,qc2.z,qc2.w, qc3.x,qc3.y,qc3.z,qc3.w};
        (void)Bv;
        #pragma unroll
        for (int n = 0; n < 16; n++) {
            float dA = __expf(dt * A[n]);
            h[n] = dA * h[n] + du * Bm[n];
            y += h[n] * Cm[n];
        }
        y += u * Dd;
        Y[(size_t)(s * 256 + tt) * 256 + d] = f2b(y);
    }
}

extern "C" void kernel_launch(void* const* d_in, const int* in_sizes, int n_in,
                              void* d_out, int out_size, void* d_ws, size_t ws_size,
                              hipStream_t stream) {
    const float* x      = (const float*)d_in[0];
    const float* g1     = (const float*)d_in[1];
    const float* b1     = (const float*)d_in[2];
    const float* W_in   = (const float*)d_in[3];
    const float* conv_w = (const float*)d_in[4];
    const float* conv_b = (const float*)d_in[5];
    const float* Wx     = (const float*)d_in[6];
    const float* Wdt    = (const float*)d_in[7];
    const float* bdt    = (const float*)d_in[8];
    const float* A_log  = (const float*)d_in[9];
    const float* Dvec   = (const float*)d_in[10];
    const float* conv_wb= (const float*)d_in[11];
    const float* conv_bb= (const float*)d_in[12];
    const float* Wxb    = (const float*)d_in[13];
    const float* Wdtb   = (const float*)d_in[14];
    const float* bdtb   = (const float*)d_in[15];
    const float* A_b_log= (const float*)d_in[16];
    const float* D_b    = (const float*)d_in[17];
    const float* W_out  = (const float*)d_in[18];
    const float* g2     = (const float*)d_in[19];
    const float* b2     = (const float*)d_in[20];
    const float* g3     = (const float*)d_in[21];
    const float* b3     = (const float*)d_in[22];
    const float* W1m    = (const float*)d_in[23];
    const float* b1m    = (const float*)d_in[24];
    const float* W2m    = (const float*)d_in[25];
    const float* b2m    = (const float*)d_in[26];

    // Workspace: 128 MiB of bf16 intermediates.
    bf16* ws  = (bf16*)d_ws;
    bf16* XZ  = ws;                    // [ROWS][512] bf16 = 64 MiB  [0, 64M)
    bf16* YF  = ws + 33554432UL;       // [ROWS][256] bf16 = 32 MiB  [64M, 96M)
    bf16* YB  = ws + 50331648UL;       // [ROWS][256] bf16 = 32 MiB  [96M, 128M)
    bf16* H2  = ws;                    // overlay (XZ dead after ln2res): 16 MiB
    bf16* HID = ws + 8388608UL;        // overlay: [16M, 48M)
    float* out = (float*)d_out;        // 8,388,608 fp32 = 32 MiB
    // d_out as scratch (dead before the real fp32 write of d_out):
    bf16* LN1OUT = (bf16*)d_out;       // [ROWS][128] bf16 = 16 MiB (dead after W_in GEMM)
    bf16* XDBL_F = (bf16*)d_out;       // [ROWS][40] bf16 = 5.24 MiB
    bf16* XDBL_B = (bf16*)d_out + 2621440UL;   // ends at 10.5 MiB

    // 1. LN1 -> d_out scratch (bf16)
    ln1_kernel<<<ROWS / 4, 256, 0, stream>>>(x, g1, b1, LN1OUT);
    // 2. XZ = LN1OUT @ W_in.T  [65536 x 512]  (MFMA)
    mfma_gemm_kernel<true, 0, 4><<<dim3(ROWS / 64, 8), 256, 0, stream>>>(
        LN1OUT, CC, W_in, nullptr, XZ, 512, 512, CC);
    // 3. xdbl (fwd/bwd) with fused conv+SiLU A-staging -> d_out scratch (bf16)
    gemm_conv_kernel<0><<<ROWS / 64, 256, 0, stream>>>(XZ, conv_w, conv_b, Wx, XDBL_F);
    gemm_conv_kernel<1><<<ROWS / 64, 256, 0, stream>>>(XZ, conv_wb, conv_bb, Wxb, XDBL_B);
    // 4. direction-parallel scan -> YF, YB (raw y per direction)
    scan_kernel<<<512, 256, 0, stream>>>(XZ, XDBL_F, XDBL_B,
        conv_w, conv_b, Wdt, bdt, A_log, Dvec,
        conv_wb, conv_bb, Wdtb, bdtb, A_b_log, D_b, YF, YB);
    // 5. yproj = ((YF+YB)*silu(z)) @ W_out.T, fused LN2 + residual -> d_out fp32 (MFMA)
    mfma_ln2res_kernel<<<ROWS / 64, 256, 0, stream>>>(YF, YB, XZ, W_out, g2, b2, x, out);
    // 6. H2 = LN3(xo) -> ws (XZ dead)
    ln3_kernel<<<ROWS / 4, 256, 0, stream>>>(out, g3, b3, H2);
    // 7. HID = gelu(H2 @ W1m + b1m)  [65536 x 256]  (MFMA)
    mfma_gemm_kernel<false, 1, 4><<<dim3(ROWS / 64, 4), 256, 0, stream>>>(
        H2, CC, W1m, b1m, HID, 2 * CC, 2 * CC, CC);
    // 8. d_out += HID @ W2m + b2m  (MFMA, fp32 accumulate)
    mfma_gemm_kernel<false, 2, 8><<<dim3(ROWS / 64, 2), 256, 0, stream>>>(
        HID, 2 * CC, W2m, b2m, out, CC, CC, 2 * CC);
}

// Round 9
// 587.155 us; speedup vs baseline: 1.6880x; 1.1109x over previous
//
#include <hip/hip_runtime.h>
#include <hip/hip_bf16.h>
#include <math.h>

// Problem dims
#define CC 128          // C
#define DI 256          // D_INNER
#define SSEQ 256        // B*N sequences
#define ROWS 65536      // SSEQ*TT

typedef __hip_bfloat16 bf16;
typedef __attribute__((ext_vector_type(8))) short short8;   // 8 bf16 (4 VGPRs) MFMA A/B frag
typedef __attribute__((ext_vector_type(4))) float float4v;  // MFMA C/D frag

__device__ __forceinline__ float to_f(float v) { return v; }
__device__ __forceinline__ float to_f(bf16 v)  { return __bfloat162float(v); }
__device__ __forceinline__ bf16  f2b(float v)  { return __float2bfloat16(v); }
__device__ __forceinline__ float bf2f_bits(short v) {
    union { unsigned u; float f; } c; c.u = ((unsigned)(unsigned short)v) << 16; return c.f;
}

__device__ __forceinline__ float wave_sum(float v) {
    #pragma unroll
    for (int o = 1; o < 64; o <<= 1) v += __shfl_xor(v, o, 64);
    return v;
}
__device__ __forceinline__ float silu_f(float x) {
    return x * __builtin_amdgcn_rcpf(1.f + __expf(-x));
}
__device__ __forceinline__ float gelu_f(float x) { return 0.5f * x * (1.f + erff(x * 0.70710678118654752f)); }
__device__ __forceinline__ float softplus_f(float x) {
    return (x > 20.f) ? x : __logf(1.f + __expf(x));
}

// ---------------- LN1: x (B,T,N,C) fp32 -> bf16 rows in (s,t) order, s = b*64+n ----------------
__global__ __launch_bounds__(256) void ln1_kernel(const float* __restrict__ x,
                                                  const float* __restrict__ g,
                                                  const float* __restrict__ b,
                                                  bf16* __restrict__ out) {
    int wave = threadIdx.x >> 6, lane = threadIdx.x & 63;
    int r = blockIdx.x * 4 + wave;
    int s = r >> 8, t = r & 255;
    int bb = s >> 6, n = s & 63;
    size_t xbase = (((size_t)(bb * 256 + t)) * 64 + n) * CC;
    float v0 = x[xbase + lane], v1 = x[xbase + lane + 64];
    float s1 = wave_sum(v0 + v1);
    float s2 = wave_sum(v0 * v0 + v1 * v1);
    float m = s1 * (1.f / 128.f);
    float var = s2 * (1.f / 128.f) - m * m;
    float rstd = rsqrtf(var + 1e-5f);
    size_t ob = (size_t)r * CC;
    out[ob + lane]      = f2b((v0 - m) * rstd * g[lane]      + b[lane]);
    out[ob + lane + 64] = f2b((v1 - m) * rstd * g[lane + 64] + b[lane + 64]);
}

// ---------------- LN3: fp32 row-major in -> bf16 out ----------------
__global__ __launch_bounds__(256) void ln3_kernel(const float* __restrict__ in,
                                                  const float* __restrict__ g,
                                                  const float* __restrict__ b,
                                                  bf16* __restrict__ out) {
    int wave = threadIdx.x >> 6, lane = threadIdx.x & 63;
    int r = blockIdx.x * 4 + wave;
    size_t ib = (size_t)r * CC;
    float v0 = in[ib + lane], v1 = in[ib + lane + 64];
    float s1 = wave_sum(v0 + v1);
    float s2 = wave_sum(v0 * v0 + v1 * v1);
    float m = s1 * (1.f / 128.f);
    float var = s2 * (1.f / 128.f) - m * m;
    float rstd = rsqrtf(var + 1e-5f);
    out[ib + lane]      = f2b((v0 - m) * rstd * g[lane]      + b[lane]);
    out[ib + lane + 64] = f2b((v1 - m) * rstd * g[lane + 64] + b[lane + 64]);
}

// ================= MFMA GEMM, 64x64 tile, 256 threads (4 waves) =================
template <bool BTR, int EPI, int KTILES>
__global__ __launch_bounds__(256) void mfma_gemm_kernel(const bf16* __restrict__ A, int lda,
                                                        const float* __restrict__ B,
                                                        const float* __restrict__ bias,
                                                        void* __restrict__ Cout, int ldc,
                                                        int N, int K) {
    __shared__ bf16 As[64][40];
    __shared__ bf16 Bs[64][40];
    int tid = threadIdx.x;
    int m0 = blockIdx.x * 64;
    int n0 = blockIdx.y * 64;
    int wv = tid >> 6, lane = tid & 63;
    int lrow = lane & 15, quad = lane >> 4;
    int lk = quad * 8;
    float4v acc[4] = {};
    #pragma unroll
    for (int kt = 0; kt < KTILES; kt++) {
        int k0 = kt * 32;
        {
            int m = tid >> 2, part = tid & 3;
            uint4 v = *(const uint4*)(A + (size_t)(m0 + m) * lda + k0 + part * 8);
            *(uint4*)&As[m][part * 8] = v;
        }
        if (BTR) {
            int n = tid >> 2, part = tid & 3;
            const float* src = B + (size_t)(n0 + n) * K + k0 + part * 8;
            bf16 tmp[8];
            #pragma unroll
            for (int j = 0; j < 8; j++) tmp[j] = f2b(src[j]);
            *(uint4*)&Bs[n][part * 8] = *(uint4*)tmp;
        } else {
            int kk = tid >> 3, nf = (tid & 7) * 8;
            const float* src = B + (size_t)(k0 + kk) * N + n0 + nf;
            #pragma unroll
            for (int j = 0; j < 8; j++) Bs[nf + j][kk] = f2b(src[j]);
        }
        __syncthreads();
        short8 a = *(const short8*)&As[wv * 16 + lrow][lk];
        #pragma unroll
        for (int jt = 0; jt < 4; jt++) {
            short8 bfr = *(const short8*)&Bs[jt * 16 + lrow][lk];
            acc[jt] = __builtin_amdgcn_mfma_f32_16x16x32_bf16(a, bfr, acc[jt], 0, 0, 0);
        }
        __syncthreads();
    }
    #pragma unroll
    for (int jt = 0; jt < 4; jt++) {
        int col = n0 + jt * 16 + lrow;
        float bs = (EPI >= 1) ? bias[col] : 0.f;
        #pragma unroll
        for (int r = 0; r < 4; r++) {
            int row = m0 + wv * 16 + quad * 4 + r;
            float v = acc[jt][r] + bs;
            if (EPI == 1) v = gelu_f(v);
            if (EPI == 2) {
                float* Cf = (float*)Cout;
                Cf[(size_t)row * ldc + col] += v;
            } else {
                bf16* Cb = (bf16*)Cout;
                Cb[(size_t)row * ldc + col] = f2b(v);
            }
        }
    }
}

// ======== MFMA W_out GEMM (64x128 tile), A = (YF+YB)*silu(z), fused LN2 + residual ========
__global__ __launch_bounds__(256) void mfma_ln2res_kernel(const bf16* __restrict__ YF,
                                                          const bf16* __restrict__ YB,
                                                          const bf16* __restrict__ xz,
                                                          const float* __restrict__ Wout,
                                                          const float* __restrict__ g,
                                                          const float* __restrict__ b,
                                                          const float* __restrict__ x,
                                                          float* __restrict__ out) {
    __shared__ bf16 As[64][40];
    __shared__ bf16 Bs[128][40];
    int tid = threadIdx.x;
    int m0 = blockIdx.x * 64;
    int wv = tid >> 6, lane = tid & 63;
    int lrow = lane & 15, quad = lane >> 4;
    int lk = quad * 8;
    float4v acc[8] = {};
    #pragma unroll
    for (int kt = 0; kt < 8; kt++) {          // K = 256
        int k0 = kt * 32;
        {
            int m = tid >> 2, part = tid & 3;
            size_t off = (size_t)(m0 + m) * 256 + k0 + part * 8;
            short8 vf = *(const short8*)(YF + off);
            short8 vb = *(const short8*)(YB + off);
            short8 vz = *(const short8*)(xz + (size_t)(m0 + m) * 512 + 256 + k0 + part * 8);
            bf16 tmp[8];
            #pragma unroll
            for (int j = 0; j < 8; j++)
                tmp[j] = f2b((bf2f_bits(vf[j]) + bf2f_bits(vb[j])) * silu_f(bf2f_bits(vz[j])));
            *(uint4*)&As[m][part * 8] = *(uint4*)tmp;
        }
        #pragma unroll
        for (int it = 0; it < 2; it++) {
            int idx = tid + it * 256;
            int n = idx >> 2, part = idx & 3;
            const float* src = Wout + (size_t)n * 256 + k0 + part * 8;
            bf16 tmp[8];
            #pragma unroll
            for (int j = 0; j < 8; j++) tmp[j] = f2b(src[j]);
            *(uint4*)&Bs[n][part * 8] = *(uint4*)tmp;
        }
        __syncthreads();
        short8 a = *(const short8*)&As[wv * 16 + lrow][lk];
        #pragma unroll
        for (int jt = 0; jt < 8; jt++) {
            short8 bfr = *(const short8*)&Bs[jt * 16 + lrow][lk];
            acc[jt] = __builtin_amdgcn_mfma_f32_16x16x32_bf16(a, bfr, acc[jt], 0, 0, 0);
        }
        __syncthreads();
    }
    #pragma unroll
    for (int r = 0; r < 4; r++) {
        float ps = 0.f, ps2 = 0.f;
        #pragma unroll
        for (int jt = 0; jt < 8; jt++) { float v = acc[jt][r]; ps += v; ps2 += v * v; }
        #pragma unroll
        for (int o = 1; o < 16; o <<= 1) {
            ps  += __shfl_xor(ps, o, 64);
            ps2 += __shfl_xor(ps2, o, 64);
        }
        float m = ps * (1.f / 128.f);
        float var = ps2 * (1.f / 128.f) - m * m;
        float rstd = rsqrtf(var + 1e-5f);
        int row = m0 + wv * 16 + quad * 4 + r;
        int s = row >> 8, t = row & 255;
        int bb = s >> 6, n = s & 63;
        size_t xbase = (((size_t)(bb * 256 + t)) * 64 + n) * CC;
        #pragma unroll
        for (int jt = 0; jt < 8; jt++) {
            int col = jt * 16 + lrow;
            out[xbase + col] = (acc[jt][r] - m) * rstd * g[col] + b[col] + x[xbase + col];
        }
    }
}

// ======== MFMA xdbl GEMM with fused causal conv + SiLU A-staging ========
// C[s*256+t][0..40) = silu(conv(xc))[t] @ Wx.T.  Block = 64 rows of one sequence.
// Grid 1024: blockIdx = s*4 + tile (t0 = tile*64).  DIR selects time mapping.
template <int DIR>
__global__ __launch_bounds__(256) void mfma_conv_kernel(const bf16* __restrict__ xz,
                                                        const float* __restrict__ cw,
                                                        const float* __restrict__ cb,
                                                        const float* __restrict__ Wx,
                                                        bf16* __restrict__ C) {
    __shared__ bf16 As[64][40];
    __shared__ bf16 Bs[48][40];
    int tid = threadIdx.x;
    int s = blockIdx.x >> 2;
    int t0 = (blockIdx.x & 3) * 64;
    int wv = tid >> 6, lane = tid & 63;
    int lrow = lane & 15, quad = lane >> 4;
    int lk = quad * 8;
    float4v acc[3] = {};
    #pragma unroll
    for (int kt = 0; kt < 8; kt++) {          // K = 256 channels
        int k0 = kt * 32;
        // ---- A-stage: fused 4-tap conv + SiLU -> bf16, thread covers (row m, 8 channels) ----
        {
            int m = tid >> 2, part = tid & 3;
            int t = t0 + m;
            int dbase = k0 + part * 8;
            float a[8];
            float4 w4[8];
            #pragma unroll
            for (int i = 0; i < 8; i++) {
                a[i]  = cb[dbase + i];
                w4[i] = ((const float4*)cw)[dbase + i];   // cw[d][0..3]
            }
            #pragma unroll
            for (int j = 0; j < 4; j++) {
                int tj = t - 3 + j;
                if (tj >= 0) {
                    int src = DIR ? (255 - tj) : tj;
                    uint4 v = *(const uint4*)(xz + (size_t)(s * 256 + src) * 512 + dbase);
                    short8 sv = *(short8*)&v;
                    #pragma unroll
                    for (int i = 0; i < 8; i++) {
                        float w = (j == 0) ? w4[i].x : (j == 1) ? w4[i].y : (j == 2) ? w4[i].z : w4[i].w;
                        a[i] += w * bf2f_bits(sv[i]);
                    }
                }
            }
            bf16 tmp[8];
            #pragma unroll
            for (int i = 0; i < 8; i++) tmp[i] = f2b(silu_f(a[i]));
            *(uint4*)&As[m][part * 8] = *(uint4*)tmp;
        }
        // ---- B-stage: Wx [40][256] fp32 -> Bs[48][32] bf16 (rows 40-47 zero) ----
        {
            int n = tid >> 2, part = tid & 3;
            if (n < 48) {
                bf16 tmp[8];
                #pragma unroll
                for (int j = 0; j < 8; j++)
                    tmp[j] = (n < 40) ? f2b(Wx[(size_t)n * 256 + k0 + part * 8 + j]) : f2b(0.f);
                *(uint4*)&Bs[n][part * 8] = *(uint4*)tmp;
            }
        }
        __syncthreads();
        short8 a = *(const short8*)&As[wv * 16 + lrow][lk];
        #pragma unroll
        for (int jt = 0; jt < 3; jt++) {
            short8 bfr = *(const short8*)&Bs[jt * 16 + lrow][lk];
            acc[jt] = __builtin_amdgcn_mfma_f32_16x16x32_bf16(a, bfr, acc[jt], 0, 0, 0);
        }
        __syncthreads();
    }
    #pragma unroll
    for (int jt = 0; jt < 3; jt++) {
        int col = jt * 16 + lrow;
        if (col < 40) {
            #pragma unroll
            for (int r = 0; r < 4; r++) {
                int row = t0 + wv * 16 + quad * 4 + r;
                C[(size_t)(s * 256 + row) * 40 + col] = f2b(acc[jt][r]);
            }
        }
    }
}

// ---------------- Direction-parallel selective scan v3 (unchanged from round 8) ----------------
__global__ __launch_bounds__(256) void scan_kernel(const bf16* __restrict__ xz,
        const bf16* __restrict__ xdbl_f, const bf16* __restrict__ xdbl_b,
        const float* __restrict__ cw_f, const float* __restrict__ cb_f,
        const float* __restrict__ Wdt_f, const float* __restrict__ bdt_f,
        const float* __restrict__ Alog_f, const float* __restrict__ D_f,
        const float* __restrict__ cw_b, const float* __restrict__ cb_b,
        const float* __restrict__ Wdt_b, const float* __restrict__ bdt_b,
        const float* __restrict__ Alog_b, const float* __restrict__ D_b,
        bf16* __restrict__ YF, bf16* __restrict__ YB) {
    __shared__ float rows[256 * 40];   // 40 KB fp32
    int tid = threadIdx.x;
    int dir = blockIdx.x >> 8;
    int s = blockIdx.x & 255;
    int d = tid;

    const bf16* xd = (dir ? xdbl_b : xdbl_f) + (size_t)s * 10240;
    #pragma unroll
    for (int i = 0; i < 5; i++) {
        int idx = i * 256 + tid;
        uint4 v = ((const uint4*)xd)[idx];
        short8 sv = *(short8*)&v;
        float f[8];
        #pragma unroll
        for (int j = 0; j < 8; j++) f[j] = bf2f_bits(sv[j]);
        *(float4*)&rows[idx * 8]     = *(float4*)&f[0];
        *(float4*)&rows[idx * 8 + 4] = *(float4*)&f[4];
    }

    const float* Alog = dir ? Alog_b : Alog_f;
    const float* Wdtp = dir ? Wdt_b  : Wdt_f;
    const float* cwp  = dir ? cw_b   : cw_f;
    float A[16], wdt[8];
    #pragma unroll
    for (int n = 0; n < 16; n++) A[n] = -__expf(Alog[d * 16 + n]);
    #pragma unroll
    for (int r = 0; r < 8; r++) wdt[r] = Wdtp[d * 8 + r];
    float bd = dir ? bdt_b[d] : bdt_f[d];
    float Dd = dir ? D_b[d]   : D_f[d];
    float cb = dir ? cb_b[d]  : cb_f[d];
    float c0 = cwp[d * 4], c1 = cwp[d * 4 + 1], c2 = cwp[d * 4 + 2], c3 = cwp[d * 4 + 3];
    bf16* Y = dir ? YB : YF;
    const bf16* xcol = xz + d;
    __syncthreads();

    float h[16];
    #pragma unroll
    for (int n = 0; n < 16; n++) h[n] = 0.f;
    float w0 = 0.f, w1 = 0.f, w2 = 0.f, w3 = 0.f;
    int o0 = dir ? 255 : 0, o1 = dir ? 254 : 1;
    float xc0 = to_f(xcol[(size_t)(s * 256 + o0) * 512]);
    float xc1 = to_f(xcol[(size_t)(s * 256 + o1) * 512]);
    for (int t = 0; t < 256; t++) {
        int tt = dir ? (255 - t) : t;
        float xc = xc0; xc0 = xc1;
        if (t + 2 < 256) {
            int onx = dir ? (253 - t) : (t + 2);
            xc1 = to_f(xcol[(size_t)(s * 256 + onx) * 512]);
        }
        const float* row = rows + t * 40;
        float4 q0 = *(const float4*)(row);
        float4 q1 = *(const float4*)(row + 4);
        float4 qb0 = *(const float4*)(row + 8);
        float4 qb1 = *(const float4*)(row + 12);
        float4 qb2 = *(const float4*)(row + 16);
        float4 qb3 = *(const float4*)(row + 20);
        float4 qc0 = *(const float4*)(row + 24);
        float4 qc1 = *(const float4*)(row + 28);
        float4 qc2 = *(const float4*)(row + 32);
        float4 qc3 = *(const float4*)(row + 36);
        w0 = w1; w1 = w2; w2 = w3; w3 = xc;
        float u = silu_f(cb + c0 * w0 + c1 * w1 + c2 * w2 + c3 * w3);
        float dtr = bd;
        dtr += q0.x * wdt[0] + q0.y * wdt[1] + q0.z * wdt[2] + q0.w * wdt[3];
        dtr += q1.x * wdt[4] + q1.y * wdt[5] + q1.z * wdt[6] + q1.w * wdt[7];
        float dt = softplus_f(dtr);
        float du = dt * u, y = 0.f;
        float Bm[16] = {qb0.x,qb0.y,qb0.z,qb0.w, qb1.x,qb1.y,qb1.z,qb1.w,
                        qb2.x,qb2.y,qb2.z,qb2.w, qb3.x,qb3.y,qb3.z,qb3.w};
        float Cm[16] = {qc0.x,qc0.y,qc0.z,qc0.w, qc1.x,qc1.y,qc1.z,qc1.w,
                        qc2.x,qc2.y,qc2.z,qc2.w, qc3.x,qc3.y,qc3.z,qc3.w};
        #pragma unroll
        for (int n = 0; n < 16; n++) {
            float dA = __expf(dt * A[n]);
            h[n] = dA * h[n] + du * Bm[n];
            y += h[n] * Cm[n];
        }
        y += u * Dd;
        Y[(size_t)(s * 256 + tt) * 256 + d] = f2b(y);
    }
}

extern "C" void kernel_launch(void* const* d_in, const int* in_sizes, int n_in,
                              void* d_out, int out_size, void* d_ws, size_t ws_size,
                              hipStream_t stream) {
    const float* x      = (const float*)d_in[0];
    const float* g1     = (const float*)d_in[1];
    const float* b1     = (const float*)d_in[2];
    const float* W_in   = (const float*)d_in[3];
    const float* conv_w = (const float*)d_in[4];
    const float* conv_b = (const float*)d_in[5];
    const float* Wx     = (const float*)d_in[6];
    const float* Wdt    = (const float*)d_in[7];
    const float* bdt    = (const float*)d_in[8];
    const float* A_log  = (const float*)d_in[9];
    const float* Dvec   = (const float*)d_in[10];
    const float* conv_wb= (const float*)d_in[11];
    const float* conv_bb= (const float*)d_in[12];
    const float* Wxb    = (const float*)d_in[13];
    const float* Wdtb   = (const float*)d_in[14];
    const float* bdtb   = (const float*)d_in[15];
    const float* A_b_log= (const float*)d_in[16];
    const float* D_b    = (const float*)d_in[17];
    const float* W_out  = (const float*)d_in[18];
    const float* g2     = (const float*)d_in[19];
    const float* b2     = (const float*)d_in[20];
    const float* g3     = (const float*)d_in[21];
    const float* b3     = (const float*)d_in[22];
    const float* W1m    = (const float*)d_in[23];
    const float* b1m    = (const float*)d_in[24];
    const float* W2m    = (const float*)d_in[25];
    const float* b2m    = (const float*)d_in[26];

    // Workspace: 128 MiB of bf16 intermediates.
    bf16* ws  = (bf16*)d_ws;
    bf16* XZ  = ws;                    // [ROWS][512] bf16 = 64 MiB  [0, 64M)
    bf16* YF  = ws + 33554432UL;       // [ROWS][256] bf16 = 32 MiB  [64M, 96M)
    bf16* YB  = ws + 50331648UL;       // [ROWS][256] bf16 = 32 MiB  [96M, 128M)
    bf16* H2  = ws;                    // overlay (XZ dead after ln2res): 16 MiB
    bf16* HID = ws + 8388608UL;        // overlay: [16M, 48M)
    float* out = (float*)d_out;        // 8,388,608 fp32 = 32 MiB
    // d_out as scratch (dead before the real fp32 write of d_out):
    bf16* LN1OUT = (bf16*)d_out;       // [ROWS][128] bf16 = 16 MiB (dead after W_in GEMM)
    bf16* XDBL_F = (bf16*)d_out;       // [ROWS][40] bf16 = 5.24 MiB
    bf16* XDBL_B = (bf16*)d_out + 2621440UL;   // ends at 10.5 MiB

    // 1. LN1 -> d_out scratch (bf16)
    ln1_kernel<<<ROWS / 4, 256, 0, stream>>>(x, g1, b1, LN1OUT);
    // 2. XZ = LN1OUT @ W_in.T  [65536 x 512]  (MFMA)
    mfma_gemm_kernel<true, 0, 4><<<dim3(ROWS / 64, 8), 256, 0, stream>>>(
        LN1OUT, CC, W_in, nullptr, XZ, 512, 512, CC);
    // 3. xdbl (fwd/bwd): MFMA GEMM with fused conv+SiLU A-staging -> d_out scratch (bf16)
    mfma_conv_kernel<0><<<SSEQ * 4, 256, 0, stream>>>(XZ, conv_w, conv_b, Wx, XDBL_F);
    mfma_conv_kernel<1><<<SSEQ * 4, 256, 0, stream>>>(XZ, conv_wb, conv_bb, Wxb, XDBL_B);
    // 4. direction-parallel scan -> YF, YB (raw y per direction)
    scan_kernel<<<512, 256, 0, stream>>>(XZ, XDBL_F, XDBL_B,
        conv_w, conv_b, Wdt, bdt, A_log, Dvec,
        conv_wb, conv_bb, Wdtb, bdtb, A_b_log, D_b, YF, YB);
    // 5. yproj = ((YF+YB)*silu(z)) @ W_out.T, fused LN2 + residual -> d_out fp32 (MFMA)
    mfma_ln2res_kernel<<<ROWS / 64, 256, 0, stream>>>(YF, YB, XZ, W_out, g2, b2, x, out);
    // 6. H2 = LN3(xo) -> ws (XZ dead)
    ln3_kernel<<<ROWS / 4, 256, 0, stream>>>(out, g3, b3, H2);
    // 7. HID = gelu(H2 @ W1m + b1m)  [65536 x 256]  (MFMA)
    mfma_gemm_kernel<false, 1, 4><<<dim3(ROWS / 64, 4), 256, 0, stream>>>(
        H2, CC, W1m, b1m, HID, 2 * CC, 2 * CC, CC);
    // 8. d_out += HID @ W2m + b2m  (MFMA, fp32 accumulate)
    mfma_gemm_kernel<false, 2, 8><<<dim3(ROWS / 64, 2), 256, 0, stream>>>(
        HID, 2 * CC, W2m, b2m, out, CC, CC, 2 * CC);
}